// Round 7
// baseline (864.305 us; speedup 1.0000x reference)
//
#include <hip/hip_runtime.h>

typedef unsigned short ushort_t;
typedef unsigned long long u64_t;
typedef __attribute__((ext_vector_type(8))) short v8bf;
typedef __attribute__((ext_vector_type(8))) unsigned short v8us;
typedef __attribute__((ext_vector_type(4))) float v4f;

#define BROWS 4096
#define DIMK 256
#define QN 32768
#define EXPSCALE 14.426950408889634f   // 10 * log2(e)

__device__ __forceinline__ ushort_t f2bf(float f) {
    unsigned u = __float_as_uint(f);
    return (ushort_t)((u + 0x7FFFu + ((u >> 16) & 1u)) >> 16);   // RNE
}
__device__ __forceinline__ u64_t shfl_xor_u64(u64_t v, int off) {
    unsigned lo = (unsigned)(v & 0xFFFFFFFFull);
    unsigned hi = (unsigned)(v >> 32);
    lo = (unsigned)__shfl_xor((int)lo, off, 64);
    hi = (unsigned)__shfl_xor((int)hi, off, 64);
    return ((u64_t)hi << 32) | (u64_t)lo;
}
#define GLOAD(g, l_) __builtin_amdgcn_global_load_lds(                         \
    (const __attribute__((address_space(1))) void*)(g),                        \
    (__attribute__((address_space(3))) void*)(l_), 16, 0, 0)

// ---- bf16 conversion of the queue ----
__global__ __launch_bounds__(256) void conv_bf16(const float* __restrict__ in,
                                                 ushort_t* __restrict__ out) {
    const size_t i = ((size_t)blockIdx.x * 256 + threadIdx.x) * 8;
    float4 x = *(const float4*)&in[i];
    float4 y = *(const float4*)&in[i + 4];
    v8us o;
    o[0] = f2bf(x.x); o[1] = f2bf(x.y); o[2] = f2bf(x.z); o[3] = f2bf(x.w);
    o[4] = f2bf(y.x); o[5] = f2bf(y.y); o[6] = f2bf(y.z); o[7] = f2bf(y.w);
    *(v8us*)&out[i] = o;
}

// ---- projections (fp32 VALU, 16 rows/block, grid.y selects f1/f2) ----
__global__ __launch_bounds__(256) void proj_relu16(const float* __restrict__ F1,
                                                   const float* __restrict__ F2,
                                                   const float* __restrict__ W,
                                                   const float* __restrict__ bias,
                                                   float* __restrict__ H) {
    __shared__ float fr[16][256];
    const float* F = blockIdx.y ? F2 : F1;
    float* Ho = H + (size_t)blockIdx.y * BROWS * DIMK;
    const int r0 = blockIdx.x << 4, j = threadIdx.x;
#pragma unroll
    for (int r = 0; r < 16; ++r) fr[r][j] = F[(size_t)(r0 + r) * DIMK + j];
    __syncthreads();
    float acc[16];
    const float bj = bias[j];
#pragma unroll
    for (int r = 0; r < 16; ++r) acc[r] = bj;
    for (int k = 0; k < DIMK; k += 4) {
        const float w0 = W[(k + 0) * DIMK + j];
        const float w1 = W[(k + 1) * DIMK + j];
        const float w2 = W[(k + 2) * DIMK + j];
        const float w3 = W[(k + 3) * DIMK + j];
#pragma unroll
        for (int r = 0; r < 16; ++r) {
            float4 f = *(const float4*)&fr[r][k];
            acc[r] = fmaf(f.x, w0, acc[r]);
            acc[r] = fmaf(f.y, w1, acc[r]);
            acc[r] = fmaf(f.z, w2, acc[r]);
            acc[r] = fmaf(f.w, w3, acc[r]);
        }
    }
#pragma unroll
    for (int r = 0; r < 16; ++r)
        Ho[(size_t)(r0 + r) * DIMK + j] = acc[r] > 0.f ? acc[r] : 0.f;
}

__global__ __launch_bounds__(256) void proj_norm16(const float* __restrict__ H,
                                                   const float* __restrict__ W,
                                                   const float* __restrict__ bias,
                                                   ushort_t* __restrict__ P) {
    __shared__ float hr[16][256];
    __shared__ float partial[4][16];
    const float* Hi = H + (size_t)blockIdx.y * BROWS * DIMK;
    ushort_t* Po = P + (size_t)blockIdx.y * BROWS * DIMK;
    const int r0 = blockIdx.x << 4, j = threadIdx.x;
    const int w = j >> 6, l = j & 63;
#pragma unroll
    for (int r = 0; r < 16; ++r) hr[r][j] = Hi[(size_t)(r0 + r) * DIMK + j];
    __syncthreads();
    float acc[16];
    const float bj = bias[j];
#pragma unroll
    for (int r = 0; r < 16; ++r) acc[r] = bj;
    for (int k = 0; k < DIMK; k += 4) {
        const float w0 = W[(k + 0) * DIMK + j];
        const float w1 = W[(k + 1) * DIMK + j];
        const float w2 = W[(k + 2) * DIMK + j];
        const float w3 = W[(k + 3) * DIMK + j];
#pragma unroll
        for (int r = 0; r < 16; ++r) {
            float4 f = *(const float4*)&hr[r][k];
            acc[r] = fmaf(f.x, w0, acc[r]);
            acc[r] = fmaf(f.y, w1, acc[r]);
            acc[r] = fmaf(f.z, w2, acc[r]);
            acc[r] = fmaf(f.w, w3, acc[r]);
        }
    }
#pragma unroll
    for (int r = 0; r < 16; ++r) {
        float s = acc[r] * acc[r];
        s += __shfl_xor(s, 1);  s += __shfl_xor(s, 2);
        s += __shfl_xor(s, 4);  s += __shfl_xor(s, 8);
        s += __shfl_xor(s, 16); s += __shfl_xor(s, 32);
        if (l == 0) partial[w][r] = s;
    }
    __syncthreads();
#pragma unroll
    for (int r = 0; r < 16; ++r) {
        const float tot = partial[0][r] + partial[1][r] + partial[2][r] + partial[3][r];
        const float inv = 1.f / fmaxf(sqrtf(tot), 1e-12f);
        Po[(size_t)(r0 + r) * DIMK + j] = f2bf(acc[r] * inv);
    }
}

// ---- stage nch*32 rows x 64 k (bf16). LDS dest linear (gload_lds HW: base+lane*16);
// global source pre-swizzled: phys octet (l&7) holds logical octet (l&7)^(row&7).
__device__ __forceinline__ void stage(const ushort_t* __restrict__ M, int grow0,
                                      int kelem, ushort_t* lds, int w, int l, int nch) {
#pragma unroll
    for (int j = 0; j < 8; ++j) {
        if (j >= nch) break;
        const int row = (j << 5) + (w << 3) + (l >> 3);
        const int oct = (l & 7) ^ (l >> 3);
        GLOAD(&M[(size_t)(grow0 + row) * DIMK + kelem + (oct << 3)],
              lds + (j << 11) + (w << 9));
    }
}

// read one MFMA fragment from a swizzled [R][64] tile
__device__ __forceinline__ v8bf frag(const ushort_t* lds, int row, int ks) {
    const int phys = ks ^ (row & 7);
    return *(const v8bf*)&lds[(row << 6) + (phys << 3)];
}

// ---- R2-style 2-barrier t-loop GEMM. block 128x256, 4 waves (2Mx2N), wave 64x128.
// MODE 0: fused argmax over N-chunk (A=Pcat[8192], B=Q)  MODE 1: exp-sums + diag
// MODE0 decode: xcd=bid&7 -> half (A 2MB) + chunk-quad; chunk varies slowest ->
// resident L2 working set per XCD ~= 2MB A + ~1.5MB Q-chunks <= 4MB L2.
template <int MODE, int NT>
__global__ __launch_bounds__(256, 3) void nn_lse(const ushort_t* __restrict__ Abase,
                                                 const ushort_t* __restrict__ Bbase,
                                                 u64_t* __restrict__ packed,
                                                 float* __restrict__ sums,
                                                 float* __restrict__ diag) {
    __shared__ __align__(16) ushort_t As[128 * 64];   // 16 KB
    __shared__ __align__(16) ushort_t Bs[256 * 64];   // 32 KB
    const int tid = threadIdx.x;
    const int w = tid >> 6, l = tid & 63;
    const int wr = w >> 1, wc = w & 1;   // wave tile 64 rows x 128 cols

    int arow0, chunkcol;
    const ushort_t* A; const ushort_t* B;
    u64_t* pk_out = nullptr;
    float* sr = nullptr; float* sc = nullptr; float* dg = nullptr;
    if (MODE == 0) {
        const int bid = blockIdx.x;                 // 2048 blocks
        const int xcd = bid & 7, i = bid >> 3;      // i in 0..255
        const int half = xcd & 1;                   // XCD parity -> which projection
        const int pairgrp = xcd >> 1;               // 0..3, owns 8 col chunks
        const int chunk = (pairgrp << 3) + (i >> 5);  // 32 chunks of 1024 cols
        arow0 = (i & 31) << 7;                      // 32 row-blocks of 128
        chunkcol = chunk << 10;
        A = Abase + (size_t)half * BROWS * DIMK;
        B = Bbase;
        pk_out = packed + (size_t)half * BROWS;
    } else {
        const int z = blockIdx.z;
        arow0 = (int)blockIdx.y << 7;
        chunkcol = (int)blockIdx.x << 10;           // 4 chunks of 1024 cols
        A = Abase + (size_t)z * BROWS * DIMK;
        B = Bbase + (size_t)(1 - z) * BROWS * DIMK;
        sr = sums + (size_t)(2 * z) * BROWS;
        sc = sums + (size_t)(2 * z + 1) * BROWS;
        dg = diag + (size_t)z * BROWS;
    }

    unsigned wbest[4][4];
    int tbest[4][4];
    float rsum[4][4];
#pragma unroll
    for (int a = 0; a < 4; ++a)
#pragma unroll
        for (int r = 0; r < 4; ++r) { wbest[a][r] = 0u; tbest[a][r] = 0; rsum[a][r] = 0.f; }

    for (int t = 0; t < NT; ++t) {
        v4f acc[4][8];
        const float cinit = (MODE == 0) ? 2.0f : 0.0f;   // +2 bias -> positive, uint-monotone
#pragma unroll
        for (int a = 0; a < 4; ++a)
#pragma unroll
            for (int b = 0; b < 8; ++b) acc[a][b] = (v4f){cinit, cinit, cinit, cinit};

#pragma unroll
        for (int k0 = 0; k0 < 4; ++k0) {
            const int kelem = k0 << 6;
            stage(A, arow0, kelem, As, w, l, 4);
            stage(B, chunkcol + (t << 8), kelem, Bs, w, l, 8);
            __syncthreads();
#pragma unroll
            for (int hh = 0; hh < 2; ++hh) {
                const int ks = (hh << 2) + (l >> 4);
                v8bf av[4], bv[8];
#pragma unroll
                for (int mi = 0; mi < 4; ++mi)
                    av[mi] = frag(As, (wr << 6) + (mi << 4) + (l & 15), ks);
#pragma unroll
                for (int nj = 0; nj < 8; ++nj)
                    bv[nj] = frag(Bs, (wc << 7) + (nj << 4) + (l & 15), ks);
#pragma unroll
                for (int mi = 0; mi < 4; ++mi)
#pragma unroll
                    for (int nj = 0; nj < 8; ++nj)
                        acc[mi][nj] = __builtin_amdgcn_mfma_f32_16x16x32_bf16(
                            av[mi], bv[nj], acc[mi][nj], 0, 0, 0);
            }
            __syncthreads();
        }

        if (MODE == 0) {
            // packed running argmax: (bits(v+2) & ~7) | nj, uint-max; track t separately
#pragma unroll
            for (int mi = 0; mi < 4; ++mi)
#pragma unroll
                for (int r = 0; r < 4; ++r) {
                    unsigned m = __float_as_uint(acc[mi][0][r]) & 0xFFFFFFF8u;
#pragma unroll
                    for (int nj = 1; nj < 8; ++nj) {
                        unsigned c = (__float_as_uint(acc[mi][nj][r]) & 0xFFFFFFF8u) | (unsigned)nj;
                        m = c > m ? c : m;
                    }
                    if (m > wbest[mi][r]) { wbest[mi][r] = m; tbest[mi][r] = t; }
                }
        } else {
            const int cb = chunkcol + (t << 8);
            // diag from raw scores (before exp)
#pragma unroll
            for (int mi = 0; mi < 4; ++mi)
#pragma unroll
                for (int nj = 0; nj < 8; ++nj) {
                    const int gr16 = arow0 + (wr << 6) + (mi << 4);
                    const int gc16 = cb + (wc << 7) + (nj << 4);
                    if (gr16 == gc16) {
#pragma unroll
                        for (int r = 0; r < 4; ++r) {
                            const int rr = ((l >> 4) << 2) + r;
                            if ((l & 15) == rr) dg[gr16 + rr] = acc[mi][nj][r] * 10.0f;
                        }
                    }
                }
            // exp in place, accumulate row sums in regs, col sums via per-t atomic
#pragma unroll
            for (int mi = 0; mi < 4; ++mi)
#pragma unroll
                for (int nj = 0; nj < 8; ++nj) {
                    v4f tv = acc[mi][nj];
                    tv[0] = exp2f(tv[0] * EXPSCALE);
                    tv[1] = exp2f(tv[1] * EXPSCALE);
                    tv[2] = exp2f(tv[2] * EXPSCALE);
                    tv[3] = exp2f(tv[3] * EXPSCALE);
                    acc[mi][nj] = tv;
                }
#pragma unroll
            for (int mi = 0; mi < 4; ++mi)
#pragma unroll
                for (int r = 0; r < 4; ++r) {
                    float s = 0.f;
#pragma unroll
                    for (int nj = 0; nj < 8; ++nj) s += acc[mi][nj][r];
                    rsum[mi][r] += s;
                }
#pragma unroll
            for (int nj = 0; nj < 8; ++nj) {
                float s = 0.f;
#pragma unroll
                for (int mi = 0; mi < 4; ++mi)
#pragma unroll
                    for (int r = 0; r < 4; ++r) s += acc[mi][nj][r];
                s += __shfl_xor(s, 16); s += __shfl_xor(s, 32);
                if (l < 16) atomicAdd(&sc[cb + (wc << 7) + (nj << 4) + l], s);
            }
        }
    }

    if (MODE == 0) {
#pragma unroll
        for (int mi = 0; mi < 4; ++mi)
#pragma unroll
            for (int r = 0; r < 4; ++r) {
                const unsigned wb = wbest[mi][r];
                const unsigned col = (unsigned)(chunkcol + (tbest[mi][r] << 8) + (wc << 7) +
                                                (int)((wb & 7u) << 4)) + (l & 15);
                u64_t pk = ((u64_t)wb << 32) | (u64_t)(0xFFFFFFFFu - col);
#pragma unroll
                for (int off = 1; off < 16; off <<= 1) {
                    u64_t o = shfl_xor_u64(pk, off);
                    if (o > pk) pk = o;
                }
                if ((l & 15) == 0)
                    atomicMax(&pk_out[arow0 + (wr << 6) + (mi << 4) + ((l >> 4) << 2) + r], pk);
            }
    } else {
#pragma unroll
        for (int mi = 0; mi < 4; ++mi)
#pragma unroll
            for (int r = 0; r < 4; ++r) {
                float s = rsum[mi][r];
                s += __shfl_xor(s, 1); s += __shfl_xor(s, 2);
                s += __shfl_xor(s, 4); s += __shfl_xor(s, 8);
                if ((l & 15) == 0)
                    atomicAdd(&sr[arow0 + (wr << 6) + (mi << 4) + ((l >> 4) << 2) + r], s);
            }
    }
}

// ---- gather nn rows (grid-stride) ----
__global__ __launch_bounds__(256) void gather_bf(const u64_t* __restrict__ packed,
                                                 const ushort_t* __restrict__ qb,
                                                 ushort_t* __restrict__ nn) {
    const int j = threadIdx.x;
    for (int i = blockIdx.x; i < 2 * BROWS; i += (int)gridDim.x) {
        const unsigned idx = 0xFFFFFFFFu - (unsigned)(packed[i] & 0xFFFFFFFFull);
        nn[(size_t)i * DIMK + j] = qb[(size_t)idx * DIMK + j];
    }
}

__global__ __launch_bounds__(256) void final_loss(const float* __restrict__ d1,
                                                  const float* __restrict__ d2,
                                                  const float* __restrict__ sr1,
                                                  const float* __restrict__ sc1,
                                                  const float* __restrict__ sr2,
                                                  const float* __restrict__ sc2,
                                                  float* __restrict__ out) {
    __shared__ float red[256];
    const int t = threadIdx.x;
    float acc = 0.f;
    for (int i = t; i < BROWS; i += 256) {
        acc += 2.f * (d1[i] + d2[i]) - logf(sr1[i]) - logf(sc1[i]) - logf(sr2[i]) - logf(sc2[i]);
    }
    red[t] = acc;
    __syncthreads();
    for (int s = 128; s > 0; s >>= 1) {
        if (t < s) red[t] += red[t + s];
        __syncthreads();
    }
    if (t == 0) out[0] = -red[0] / (4.0f * (float)BROWS);
}

extern "C" void kernel_launch(void* const* d_in, const int* in_sizes, int n_in,
                              void* d_out, int out_size, void* d_ws, size_t ws_size,
                              hipStream_t stream) {
    const float* f1 = (const float*)d_in[0];
    const float* f2 = (const float*)d_in[1];
    const float* W1 = (const float*)d_in[2];
    const float* b1 = (const float*)d_in[3];
    const float* W2 = (const float*)d_in[4];
    const float* b2 = (const float*)d_in[5];
    const float* queue = (const float*)d_in[6];
    float* out = (float*)d_out;

    char* ws = (char*)d_ws;
    float* h        = (float*)ws;                          // 8 MB (both halves)
    ushort_t* pcat  = (ushort_t*)(ws + (8ull << 20));      // 4 MB: p1 | p2
    ushort_t* nncat = (ushort_t*)(ws + (12ull << 20));     // 4 MB: nn1 | nn2
    ushort_t* qb    = (ushort_t*)(ws + (16ull << 20));     // 16 MB
    u64_t* packed   = (u64_t*)(ws + (32ull << 20));        // 64 KB (8192 rows)
    float* sums     = (float*)(ws + (32ull << 20) + (64ull << 10));   // 64 KB
    float* diag     = (float*)(ws + (32ull << 20) + (128ull << 10));  // 32 KB

    // zero atomic targets (packed argmax + exp sums)
    hipMemsetAsync(packed, 0, (128ull << 10), stream);

    conv_bf16<<<(QN * DIMK) / 2048, 256, 0, stream>>>(queue, qb);

    dim3 gp(BROWS / 16, 2);
    proj_relu16<<<gp, 256, 0, stream>>>(f1, f2, W1, b1, h);
    proj_norm16<<<gp, 256, 0, stream>>>(h, W2, b2, pcat);

    nn_lse<0, 4><<<2048, 256, 0, stream>>>(pcat, qb, packed, nullptr, nullptr);

    gather_bf<<<256, 256, 0, stream>>>(packed, qb, nncat);

    dim3 gl(4, 32, 2);
    nn_lse<1, 4><<<gl, 256, 0, stream>>>(nncat, pcat, nullptr, sums, diag);

    final_loss<<<1, 256, 0, stream>>>(diag, diag + BROWS,
                                      sums, sums + BROWS, sums + 2 * BROWS, sums + 3 * BROWS,
                                      out);
}

// Round 8
// 339.062 us; speedup vs baseline: 2.5491x; 2.5491x over previous
//
#include <hip/hip_runtime.h>

typedef unsigned short ushort_t;
typedef unsigned long long u64_t;
typedef __attribute__((ext_vector_type(8))) short v8bf;
typedef __attribute__((ext_vector_type(8))) unsigned short v8us;
typedef __attribute__((ext_vector_type(4))) float v4f;

#define BROWS 4096
#define DIMK 256
#define QN 32768
#define EXPSCALE 14.426950408889634f   // 10 * log2(e)

__device__ __forceinline__ ushort_t f2bf(float f) {
    unsigned u = __float_as_uint(f);
    return (ushort_t)((u + 0x7FFFu + ((u >> 16) & 1u)) >> 16);   // RNE
}
__device__ __forceinline__ u64_t shfl_xor_u64(u64_t v, int off) {
    unsigned lo = (unsigned)(v & 0xFFFFFFFFull);
    unsigned hi = (unsigned)(v >> 32);
    lo = (unsigned)__shfl_xor((int)lo, off, 64);
    hi = (unsigned)__shfl_xor((int)hi, off, 64);
    return ((u64_t)hi << 32) | (u64_t)lo;
}
#define GLOAD(g, l_) __builtin_amdgcn_global_load_lds(                         \
    (const __attribute__((address_space(1))) void*)(g),                        \
    (__attribute__((address_space(3))) void*)(l_), 16, 0, 0)

// ---- bf16 conversion of the queue ----
__global__ __launch_bounds__(256) void conv_bf16(const float* __restrict__ in,
                                                 ushort_t* __restrict__ out) {
    const size_t i = ((size_t)blockIdx.x * 256 + threadIdx.x) * 8;
    float4 x = *(const float4*)&in[i];
    float4 y = *(const float4*)&in[i + 4];
    v8us o;
    o[0] = f2bf(x.x); o[1] = f2bf(x.y); o[2] = f2bf(x.z); o[3] = f2bf(x.w);
    o[4] = f2bf(y.x); o[5] = f2bf(y.y); o[6] = f2bf(y.z); o[7] = f2bf(y.w);
    *(v8us*)&out[i] = o;
}

// ---- projections (fp32 VALU, 16 rows/block, grid.y selects f1/f2) ----
__global__ __launch_bounds__(256) void proj_relu16(const float* __restrict__ F1,
                                                   const float* __restrict__ F2,
                                                   const float* __restrict__ W,
                                                   const float* __restrict__ bias,
                                                   float* __restrict__ H) {
    __shared__ float fr[16][256];
    const float* F = blockIdx.y ? F2 : F1;
    float* Ho = H + (size_t)blockIdx.y * BROWS * DIMK;
    const int r0 = blockIdx.x << 4, j = threadIdx.x;
#pragma unroll
    for (int r = 0; r < 16; ++r) fr[r][j] = F[(size_t)(r0 + r) * DIMK + j];
    __syncthreads();
    float acc[16];
    const float bj = bias[j];
#pragma unroll
    for (int r = 0; r < 16; ++r) acc[r] = bj;
    for (int k = 0; k < DIMK; k += 4) {
        const float w0 = W[(k + 0) * DIMK + j];
        const float w1 = W[(k + 1) * DIMK + j];
        const float w2 = W[(k + 2) * DIMK + j];
        const float w3 = W[(k + 3) * DIMK + j];
#pragma unroll
        for (int r = 0; r < 16; ++r) {
            float4 f = *(const float4*)&fr[r][k];
            acc[r] = fmaf(f.x, w0, acc[r]);
            acc[r] = fmaf(f.y, w1, acc[r]);
            acc[r] = fmaf(f.z, w2, acc[r]);
            acc[r] = fmaf(f.w, w3, acc[r]);
        }
    }
#pragma unroll
    for (int r = 0; r < 16; ++r)
        Ho[(size_t)(r0 + r) * DIMK + j] = acc[r] > 0.f ? acc[r] : 0.f;
}

__global__ __launch_bounds__(256) void proj_norm16(const float* __restrict__ H,
                                                   const float* __restrict__ W,
                                                   const float* __restrict__ bias,
                                                   ushort_t* __restrict__ P) {
    __shared__ float hr[16][256];
    __shared__ float partial[4][16];
    const float* Hi = H + (size_t)blockIdx.y * BROWS * DIMK;
    ushort_t* Po = P + (size_t)blockIdx.y * BROWS * DIMK;
    const int r0 = blockIdx.x << 4, j = threadIdx.x;
    const int w = j >> 6, l = j & 63;
#pragma unroll
    for (int r = 0; r < 16; ++r) hr[r][j] = Hi[(size_t)(r0 + r) * DIMK + j];
    __syncthreads();
    float acc[16];
    const float bj = bias[j];
#pragma unroll
    for (int r = 0; r < 16; ++r) acc[r] = bj;
    for (int k = 0; k < DIMK; k += 4) {
        const float w0 = W[(k + 0) * DIMK + j];
        const float w1 = W[(k + 1) * DIMK + j];
        const float w2 = W[(k + 2) * DIMK + j];
        const float w3 = W[(k + 3) * DIMK + j];
#pragma unroll
        for (int r = 0; r < 16; ++r) {
            float4 f = *(const float4*)&hr[r][k];
            acc[r] = fmaf(f.x, w0, acc[r]);
            acc[r] = fmaf(f.y, w1, acc[r]);
            acc[r] = fmaf(f.z, w2, acc[r]);
            acc[r] = fmaf(f.w, w3, acc[r]);
        }
    }
#pragma unroll
    for (int r = 0; r < 16; ++r) {
        float s = acc[r] * acc[r];
        s += __shfl_xor(s, 1);  s += __shfl_xor(s, 2);
        s += __shfl_xor(s, 4);  s += __shfl_xor(s, 8);
        s += __shfl_xor(s, 16); s += __shfl_xor(s, 32);
        if (l == 0) partial[w][r] = s;
    }
    __syncthreads();
#pragma unroll
    for (int r = 0; r < 16; ++r) {
        const float tot = partial[0][r] + partial[1][r] + partial[2][r] + partial[3][r];
        const float inv = 1.f / fmaxf(sqrtf(tot), 1e-12f);
        Po[(size_t)(r0 + r) * DIMK + j] = f2bf(acc[r] * inv);
    }
}

// ---- stage nch*32 rows x 64 k (bf16). LDS dest linear (gload_lds HW: base+lane*16);
// global source pre-swizzled: phys octet (l&7) holds logical octet (l&7)^(row&7).
__device__ __forceinline__ void stage(const ushort_t* __restrict__ M, int grow0,
                                      int kelem, ushort_t* lds, int w, int l, int nch) {
#pragma unroll
    for (int j = 0; j < 8; ++j) {
        if (j >= nch) break;
        const int row = (j << 5) + (w << 3) + (l >> 3);
        const int oct = (l & 7) ^ (l >> 3);
        GLOAD(&M[(size_t)(grow0 + row) * DIMK + kelem + (oct << 3)],
              lds + (j << 11) + (w << 9));
    }
}

// read one MFMA fragment from a swizzled [R][64] tile
__device__ __forceinline__ v8bf frag(const ushort_t* lds, int row, int ks) {
    const int phys = ks ^ (row & 7);
    return *(const v8bf*)&lds[(row << 6) + (phys << 3)];
}

// ---- R2-style 2-barrier t-loop GEMM. block 128x256, 4 waves (2Mx2N), wave 64x128.
// MODE 0: fused argmax over N-chunk (A=P half per XCD parity, B=Q)
// MODE 1: exp-sums + diag
// MODE0 decode: xcd=bid&7 -> half (A 2MB) + chunk-quad; chunk varies slowest ->
// resident L2 working set per XCD ~= 2MB A + ~1.5MB Q-chunks <= 4MB L2.
// NOTE: launch_bounds min-waves MUST stay 2 — 3 forced VGPR<=84 and spilled the
// 128-VGPR accumulator to scratch (R7: 1.7GB scratch writes, 5x slowdown).
template <int MODE, int NT>
__global__ __launch_bounds__(256, 2) void nn_lse(const ushort_t* __restrict__ Abase,
                                                 const ushort_t* __restrict__ Bbase,
                                                 u64_t* __restrict__ packed,
                                                 float* __restrict__ sums,
                                                 float* __restrict__ diag) {
    __shared__ __align__(16) ushort_t As[128 * 64];   // 16 KB
    __shared__ __align__(16) ushort_t Bs[256 * 64];   // 32 KB
    const int tid = threadIdx.x;
    const int w = tid >> 6, l = tid & 63;
    const int wr = w >> 1, wc = w & 1;   // wave tile 64 rows x 128 cols

    int arow0, chunkcol;
    const ushort_t* A; const ushort_t* B;
    u64_t* pk_out = nullptr;
    float* sr = nullptr; float* sc = nullptr; float* dg = nullptr;
    if (MODE == 0) {
        const int bid = blockIdx.x;                 // 2048 blocks
        const int xcd = bid & 7, i = bid >> 3;      // i in 0..255
        const int half = xcd & 1;                   // XCD parity -> which projection
        const int pairgrp = xcd >> 1;               // 0..3, owns 8 col chunks
        const int chunk = (pairgrp << 3) + (i >> 5);  // 32 chunks of 1024 cols
        arow0 = (i & 31) << 7;                      // 32 row-blocks of 128
        chunkcol = chunk << 10;
        A = Abase + (size_t)half * BROWS * DIMK;
        B = Bbase;
        pk_out = packed + (size_t)half * BROWS;
    } else {
        const int z = blockIdx.z;
        arow0 = (int)blockIdx.y << 7;
        chunkcol = (int)blockIdx.x << 10;           // 4 chunks of 1024 cols
        A = Abase + (size_t)z * BROWS * DIMK;
        B = Bbase + (size_t)(1 - z) * BROWS * DIMK;
        sr = sums + (size_t)(2 * z) * BROWS;
        sc = sums + (size_t)(2 * z + 1) * BROWS;
        dg = diag + (size_t)z * BROWS;
    }

    unsigned wbest[4][4];
    int tbest[4][4];
    float rsum[4][4];
#pragma unroll
    for (int a = 0; a < 4; ++a)
#pragma unroll
        for (int r = 0; r < 4; ++r) { wbest[a][r] = 0u; tbest[a][r] = 0; rsum[a][r] = 0.f; }

    for (int t = 0; t < NT; ++t) {
        v4f acc[4][8];
        const float cinit = (MODE == 0) ? 2.0f : 0.0f;   // +2 bias -> positive, uint-monotone
#pragma unroll
        for (int a = 0; a < 4; ++a)
#pragma unroll
            for (int b = 0; b < 8; ++b) acc[a][b] = (v4f){cinit, cinit, cinit, cinit};

#pragma unroll
        for (int k0 = 0; k0 < 4; ++k0) {
            const int kelem = k0 << 6;
            stage(A, arow0, kelem, As, w, l, 4);
            stage(B, chunkcol + (t << 8), kelem, Bs, w, l, 8);
            __syncthreads();
#pragma unroll
            for (int hh = 0; hh < 2; ++hh) {
                const int ks = (hh << 2) + (l >> 4);
                v8bf av[4], bv[8];
#pragma unroll
                for (int mi = 0; mi < 4; ++mi)
                    av[mi] = frag(As, (wr << 6) + (mi << 4) + (l & 15), ks);
#pragma unroll
                for (int nj = 0; nj < 8; ++nj)
                    bv[nj] = frag(Bs, (wc << 7) + (nj << 4) + (l & 15), ks);
#pragma unroll
                for (int mi = 0; mi < 4; ++mi)
#pragma unroll
                    for (int nj = 0; nj < 8; ++nj)
                        acc[mi][nj] = __builtin_amdgcn_mfma_f32_16x16x32_bf16(
                            av[mi], bv[nj], acc[mi][nj], 0, 0, 0);
            }
            __syncthreads();
        }

        if (MODE == 0) {
            // packed running argmax: (bits(v+2) & ~7) | nj, uint-max; track t separately
#pragma unroll
            for (int mi = 0; mi < 4; ++mi)
#pragma unroll
                for (int r = 0; r < 4; ++r) {
                    unsigned m = __float_as_uint(acc[mi][0][r]) & 0xFFFFFFF8u;
#pragma unroll
                    for (int nj = 1; nj < 8; ++nj) {
                        unsigned c = (__float_as_uint(acc[mi][nj][r]) & 0xFFFFFFF8u) | (unsigned)nj;
                        m = c > m ? c : m;
                    }
                    if (m > wbest[mi][r]) { wbest[mi][r] = m; tbest[mi][r] = t; }
                }
        } else {
            const int cb = chunkcol + (t << 8);
            // diag from raw scores (before exp)
#pragma unroll
            for (int mi = 0; mi < 4; ++mi)
#pragma unroll
                for (int nj = 0; nj < 8; ++nj) {
                    const int gr16 = arow0 + (wr << 6) + (mi << 4);
                    const int gc16 = cb + (wc << 7) + (nj << 4);
                    if (gr16 == gc16) {
#pragma unroll
                        for (int r = 0; r < 4; ++r) {
                            const int rr = ((l >> 4) << 2) + r;
                            if ((l & 15) == rr) dg[gr16 + rr] = acc[mi][nj][r] * 10.0f;
                        }
                    }
                }
            // exp in place, accumulate row sums in regs, col sums via per-t atomic
#pragma unroll
            for (int mi = 0; mi < 4; ++mi)
#pragma unroll
                for (int nj = 0; nj < 8; ++nj) {
                    v4f tv = acc[mi][nj];
                    tv[0] = exp2f(tv[0] * EXPSCALE);
                    tv[1] = exp2f(tv[1] * EXPSCALE);
                    tv[2] = exp2f(tv[2] * EXPSCALE);
                    tv[3] = exp2f(tv[3] * EXPSCALE);
                    acc[mi][nj] = tv;
                }
#pragma unroll
            for (int mi = 0; mi < 4; ++mi)
#pragma unroll
                for (int r = 0; r < 4; ++r) {
                    float s = 0.f;
#pragma unroll
                    for (int nj = 0; nj < 8; ++nj) s += acc[mi][nj][r];
                    rsum[mi][r] += s;
                }
#pragma unroll
            for (int nj = 0; nj < 8; ++nj) {
                float s = 0.f;
#pragma unroll
                for (int mi = 0; mi < 4; ++mi)
#pragma unroll
                    for (int r = 0; r < 4; ++r) s += acc[mi][nj][r];
                s += __shfl_xor(s, 16); s += __shfl_xor(s, 32);
                if (l < 16) atomicAdd(&sc[cb + (wc << 7) + (nj << 4) + l], s);
            }
        }
    }

    if (MODE == 0) {
#pragma unroll
        for (int mi = 0; mi < 4; ++mi)
#pragma unroll
            for (int r = 0; r < 4; ++r) {
                const unsigned wb = wbest[mi][r];
                const unsigned col = (unsigned)(chunkcol + (tbest[mi][r] << 8) + (wc << 7) +
                                                (int)((wb & 7u) << 4)) + (l & 15);
                u64_t pk = ((u64_t)wb << 32) | (u64_t)(0xFFFFFFFFu - col);
#pragma unroll
                for (int off = 1; off < 16; off <<= 1) {
                    u64_t o = shfl_xor_u64(pk, off);
                    if (o > pk) pk = o;
                }
                if ((l & 15) == 0)
                    atomicMax(&pk_out[arow0 + (wr << 6) + (mi << 4) + ((l >> 4) << 2) + r], pk);
            }
    } else {
#pragma unroll
        for (int mi = 0; mi < 4; ++mi)
#pragma unroll
            for (int r = 0; r < 4; ++r) {
                float s = rsum[mi][r];
                s += __shfl_xor(s, 1); s += __shfl_xor(s, 2);
                s += __shfl_xor(s, 4); s += __shfl_xor(s, 8);
                if ((l & 15) == 0)
                    atomicAdd(&sr[arow0 + (wr << 6) + (mi << 4) + ((l >> 4) << 2) + r], s);
            }
    }
}

// ---- gather nn rows (grid-stride) ----
__global__ __launch_bounds__(256) void gather_bf(const u64_t* __restrict__ packed,
                                                 const ushort_t* __restrict__ qb,
                                                 ushort_t* __restrict__ nn) {
    const int j = threadIdx.x;
    for (int i = blockIdx.x; i < 2 * BROWS; i += (int)gridDim.x) {
        const unsigned idx = 0xFFFFFFFFu - (unsigned)(packed[i] & 0xFFFFFFFFull);
        nn[(size_t)i * DIMK + j] = qb[(size_t)idx * DIMK + j];
    }
}

__global__ __launch_bounds__(256) void final_loss(const float* __restrict__ d1,
                                                  const float* __restrict__ d2,
                                                  const float* __restrict__ sr1,
                                                  const float* __restrict__ sc1,
                                                  const float* __restrict__ sr2,
                                                  const float* __restrict__ sc2,
                                                  float* __restrict__ out) {
    __shared__ float red[256];
    const int t = threadIdx.x;
    float acc = 0.f;
    for (int i = t; i < BROWS; i += 256) {
        acc += 2.f * (d1[i] + d2[i]) - logf(sr1[i]) - logf(sc1[i]) - logf(sr2[i]) - logf(sc2[i]);
    }
    red[t] = acc;
    __syncthreads();
    for (int s = 128; s > 0; s >>= 1) {
        if (t < s) red[t] += red[t + s];
        __syncthreads();
    }
    if (t == 0) out[0] = -red[0] / (4.0f * (float)BROWS);
}

extern "C" void kernel_launch(void* const* d_in, const int* in_sizes, int n_in,
                              void* d_out, int out_size, void* d_ws, size_t ws_size,
                              hipStream_t stream) {
    const float* f1 = (const float*)d_in[0];
    const float* f2 = (const float*)d_in[1];
    const float* W1 = (const float*)d_in[2];
    const float* b1 = (const float*)d_in[3];
    const float* W2 = (const float*)d_in[4];
    const float* b2 = (const float*)d_in[5];
    const float* queue = (const float*)d_in[6];
    float* out = (float*)d_out;

    char* ws = (char*)d_ws;
    float* h        = (float*)ws;                          // 8 MB (both halves)
    ushort_t* pcat  = (ushort_t*)(ws + (8ull << 20));      // 4 MB: p1 | p2
    ushort_t* nncat = (ushort_t*)(ws + (12ull << 20));     // 4 MB: nn1 | nn2
    ushort_t* qb    = (ushort_t*)(ws + (16ull << 20));     // 16 MB
    u64_t* packed   = (u64_t*)(ws + (32ull << 20));        // 64 KB (8192 rows)
    float* sums     = (float*)(ws + (32ull << 20) + (64ull << 10));   // 64 KB
    float* diag     = (float*)(ws + (32ull << 20) + (128ull << 10));  // 32 KB

    // zero atomic targets (packed argmax + exp sums)
    hipMemsetAsync(packed, 0, (128ull << 10), stream);

    conv_bf16<<<(QN * DIMK) / 2048, 256, 0, stream>>>(queue, qb);

    dim3 gp(BROWS / 16, 2);
    proj_relu16<<<gp, 256, 0, stream>>>(f1, f2, W1, b1, h);
    proj_norm16<<<gp, 256, 0, stream>>>(h, W2, b2, pcat);

    nn_lse<0, 4><<<2048, 256, 0, stream>>>(pcat, qb, packed, nullptr, nullptr);

    gather_bf<<<256, 256, 0, stream>>>(packed, qb, nncat);

    dim3 gl(4, 32, 2);
    nn_lse<1, 4><<<gl, 256, 0, stream>>>(nncat, pcat, nullptr, sums, diag);

    final_loss<<<1, 256, 0, stream>>>(diag, diag + BROWS,
                                      sums, sums + BROWS, sums + 2 * BROWS, sums + 3 * BROWS,
                                      out);
}

// Round 9
// 243.910 us; speedup vs baseline: 3.5435x; 1.3901x over previous
//
#include <hip/hip_runtime.h>

typedef unsigned short ushort_t;
typedef unsigned long long u64_t;
typedef __attribute__((ext_vector_type(8))) short v8bf;
typedef __attribute__((ext_vector_type(8))) unsigned short v8us;
typedef __attribute__((ext_vector_type(4))) float v4f;

#define BROWS 4096
#define DIMK 256
#define QN 32768
#define EXPSCALE 14.426950408889634f   // 10 * log2(e)

__device__ __forceinline__ ushort_t f2bf(float f) {
    unsigned u = __float_as_uint(f);
    return (ushort_t)((u + 0x7FFFu + ((u >> 16) & 1u)) >> 16);   // RNE
}
__device__ __forceinline__ u64_t shfl_xor_u64(u64_t v, int off) {
    unsigned lo = (unsigned)(v & 0xFFFFFFFFull);
    unsigned hi = (unsigned)(v >> 32);
    lo = (unsigned)__shfl_xor((int)lo, off, 64);
    hi = (unsigned)__shfl_xor((int)hi, off, 64);
    return ((u64_t)hi << 32) | (u64_t)lo;
}
#define GLOAD(g, l_) __builtin_amdgcn_global_load_lds(                         \
    (const __attribute__((address_space(1))) void*)(g),                        \
    (__attribute__((address_space(3))) void*)(l_), 16, 0, 0)

// ---- bf16 conversion of the queue ----
__global__ __launch_bounds__(256) void conv_bf16(const float* __restrict__ in,
                                                 ushort_t* __restrict__ out) {
    const size_t i = ((size_t)blockIdx.x * 256 + threadIdx.x) * 8;
    float4 x = *(const float4*)&in[i];
    float4 y = *(const float4*)&in[i + 4];
    v8us o;
    o[0] = f2bf(x.x); o[1] = f2bf(x.y); o[2] = f2bf(x.z); o[3] = f2bf(x.w);
    o[4] = f2bf(y.x); o[5] = f2bf(y.y); o[6] = f2bf(y.z); o[7] = f2bf(y.w);
    *(v8us*)&out[i] = o;
}

// ---- projections (fp32 VALU, 16 rows/block, grid.y selects f1/f2) ----
__global__ __launch_bounds__(256) void proj_relu16(const float* __restrict__ F1,
                                                   const float* __restrict__ F2,
                                                   const float* __restrict__ W,
                                                   const float* __restrict__ bias,
                                                   float* __restrict__ H) {
    __shared__ float fr[16][256];
    const float* F = blockIdx.y ? F2 : F1;
    float* Ho = H + (size_t)blockIdx.y * BROWS * DIMK;
    const int r0 = blockIdx.x << 4, j = threadIdx.x;
#pragma unroll
    for (int r = 0; r < 16; ++r) fr[r][j] = F[(size_t)(r0 + r) * DIMK + j];
    __syncthreads();
    float acc[16];
    const float bj = bias[j];
#pragma unroll
    for (int r = 0; r < 16; ++r) acc[r] = bj;
    for (int k = 0; k < DIMK; k += 4) {
        const float w0 = W[(k + 0) * DIMK + j];
        const float w1 = W[(k + 1) * DIMK + j];
        const float w2 = W[(k + 2) * DIMK + j];
        const float w3 = W[(k + 3) * DIMK + j];
#pragma unroll
        for (int r = 0; r < 16; ++r) {
            float4 f = *(const float4*)&fr[r][k];
            acc[r] = fmaf(f.x, w0, acc[r]);
            acc[r] = fmaf(f.y, w1, acc[r]);
            acc[r] = fmaf(f.z, w2, acc[r]);
            acc[r] = fmaf(f.w, w3, acc[r]);
        }
    }
#pragma unroll
    for (int r = 0; r < 16; ++r)
        Ho[(size_t)(r0 + r) * DIMK + j] = acc[r] > 0.f ? acc[r] : 0.f;
}

__global__ __launch_bounds__(256) void proj_norm16(const float* __restrict__ H,
                                                   const float* __restrict__ W,
                                                   const float* __restrict__ bias,
                                                   ushort_t* __restrict__ P) {
    __shared__ float hr[16][256];
    __shared__ float partial[4][16];
    const float* Hi = H + (size_t)blockIdx.y * BROWS * DIMK;
    ushort_t* Po = P + (size_t)blockIdx.y * BROWS * DIMK;
    const int r0 = blockIdx.x << 4, j = threadIdx.x;
    const int w = j >> 6, l = j & 63;
#pragma unroll
    for (int r = 0; r < 16; ++r) hr[r][j] = Hi[(size_t)(r0 + r) * DIMK + j];
    __syncthreads();
    float acc[16];
    const float bj = bias[j];
#pragma unroll
    for (int r = 0; r < 16; ++r) acc[r] = bj;
    for (int k = 0; k < DIMK; k += 4) {
        const float w0 = W[(k + 0) * DIMK + j];
        const float w1 = W[(k + 1) * DIMK + j];
        const float w2 = W[(k + 2) * DIMK + j];
        const float w3 = W[(k + 3) * DIMK + j];
#pragma unroll
        for (int r = 0; r < 16; ++r) {
            float4 f = *(const float4*)&hr[r][k];
            acc[r] = fmaf(f.x, w0, acc[r]);
            acc[r] = fmaf(f.y, w1, acc[r]);
            acc[r] = fmaf(f.z, w2, acc[r]);
            acc[r] = fmaf(f.w, w3, acc[r]);
        }
    }
#pragma unroll
    for (int r = 0; r < 16; ++r) {
        float s = acc[r] * acc[r];
        s += __shfl_xor(s, 1);  s += __shfl_xor(s, 2);
        s += __shfl_xor(s, 4);  s += __shfl_xor(s, 8);
        s += __shfl_xor(s, 16); s += __shfl_xor(s, 32);
        if (l == 0) partial[w][r] = s;
    }
    __syncthreads();
#pragma unroll
    for (int r = 0; r < 16; ++r) {
        const float tot = partial[0][r] + partial[1][r] + partial[2][r] + partial[3][r];
        const float inv = 1.f / fmaxf(sqrtf(tot), 1e-12f);
        Po[(size_t)(r0 + r) * DIMK + j] = f2bf(acc[r] * inv);
    }
}

// ---- persistent-block GEMM. block 128 rows x 128-col tiles, 4 waves (2Mx2N),
// wave tile 64x64. A panel (128x256) hoisted to LDS once; B tile (128x64)
// staged per k0 (single buffer). LDS = 64+16 = 80KB -> exactly 2 blocks/CU.
// MODE 0: fused argmax, 512 blocks persistent, NT=32 (4096 cols/block)
//   decode: xcd=bid&7 -> half(A 2MB on parity), pairgrp owns 8192 cols;
//   32 row-blocks per col-half stream tiles in lockstep => L2 set ~2.3MB.
// MODE 1: exp-sums + diag, 512 blocks, NT=4 (512 cols/block).
// NOTE: min-waves stays 2 (R7: 3 forced VGPR<=84, spilled acc, 5x slowdown).
template <int MODE, int NT>
__global__ __launch_bounds__(256, 2) void nn_lse(const ushort_t* __restrict__ Abase,
                                                 const ushort_t* __restrict__ Bbase,
                                                 u64_t* __restrict__ packed,
                                                 float* __restrict__ sums,
                                                 float* __restrict__ diag) {
    __shared__ __align__(16) ushort_t Alds[128 * 256];   // 64 KB, staged once
    __shared__ __align__(16) ushort_t Bs[128 * 64];      // 16 KB, per-k0
    const int tid = threadIdx.x;
    const int w = tid >> 6, l = tid & 63;
    const int wr = w >> 1, wc = w & 1;   // wave tile 64x64

    int arow0, colbase;
    const ushort_t* A; const ushort_t* B;
    u64_t* pk_out = nullptr;
    float* sr = nullptr; float* sc = nullptr; float* dg = nullptr;
    if (MODE == 0) {
        const int bid = blockIdx.x;                // 512 blocks, all resident
        const int xcd = bid & 7, i = bid >> 3;     // i in 0..63
        const int half = xcd & 1;
        const int pairgrp = xcd >> 1;              // owns 8192 cols
        arow0 = (i & 31) << 7;                     // 32 row-blocks of 128
        colbase = (pairgrp << 13) + ((i >> 5) << 12);   // + col-half*4096
        A = Abase + (size_t)half * BROWS * DIMK;
        B = Bbase;
        pk_out = packed + (size_t)half * BROWS;
    } else {
        const int z = blockIdx.x >> 8, i = blockIdx.x & 255;
        arow0 = (i & 31) << 7;
        colbase = (i >> 5) << 9;                   // 8 strips of 512 cols
        A = Abase + (size_t)z * BROWS * DIMK;
        B = Bbase + (size_t)(1 - z) * BROWS * DIMK;
        sr = sums + (size_t)(2 * z) * BROWS;
        sc = sums + (size_t)(2 * z + 1) * BROWS;
        dg = diag + (size_t)z * BROWS;
    }

    // ---- hoist A panel: 64 wave-GLOADs of 1KB; source pre-swizzled so that
    // phys 16B slot s of row r holds logical octet (s&~7)|((s&7)^(r&7)).
#pragma unroll
    for (int j = 0; j < 16; ++j) {
        const int seg = (j << 2) + w;              // 1KB segment 0..63
        const int row = (seg << 1) + (l >> 5);     // 512B rows
        const int s = l & 31;
        const int oct = (s & ~7) | ((s & 7) ^ (row & 7));
        GLOAD(&A[(size_t)(arow0 + row) * DIMK + (oct << 3)],
              (ushort_t*)Alds + (seg << 9));
    }

    unsigned wbest[4][4];
    int tbest[4][4];
    float rsum[4][4];
#pragma unroll
    for (int a = 0; a < 4; ++a)
#pragma unroll
        for (int r = 0; r < 4; ++r) { wbest[a][r] = 0u; tbest[a][r] = 0; rsum[a][r] = 0.f; }

    for (int t = 0; t < NT; ++t) {
        v4f acc[4][4];
        const float cinit = (MODE == 0) ? 2.0f : 0.0f;   // +2 -> positive, uint-monotone
#pragma unroll
        for (int a = 0; a < 4; ++a)
#pragma unroll
            for (int b = 0; b < 4; ++b) acc[a][b] = (v4f){cinit, cinit, cinit, cinit};

#pragma unroll
        for (int k0 = 0; k0 < 4; ++k0) {
            // stage B tile (128 cols x 64 k): 16 wave-GLOADs of 1KB
#pragma unroll
            for (int j = 0; j < 4; ++j) {
                const int seg = (j << 2) + w;
                const int row = (seg << 3) + (l >> 3);   // 128B rows
                const int oct = (l & 7) ^ (row & 7);
                GLOAD(&B[(size_t)(colbase + (t << 7) + row) * DIMK + (k0 << 6) + (oct << 3)],
                      (ushort_t*)Bs + (seg << 9));
            }
            __syncthreads();   // drains vmcnt (A on first pass, B always)
#pragma unroll
            for (int hh = 0; hh < 2; ++hh) {
                v8bf av[4], bv[4];
#pragma unroll
                for (int mi = 0; mi < 4; ++mi) {
                    const int row = (wr << 6) + (mi << 4) + (l & 15);
                    const int lo = (hh << 2) + (l >> 4);
                    const int phys = (k0 << 3) | (lo ^ (row & 7));
                    av[mi] = *(const v8bf*)&Alds[(row << 8) + (phys << 3)];
                }
#pragma unroll
                for (int nj = 0; nj < 4; ++nj) {
                    const int row = (wc << 6) + (nj << 4) + (l & 15);
                    const int phys = ((hh << 2) + (l >> 4)) ^ (row & 7);
                    bv[nj] = *(const v8bf*)&Bs[(row << 6) + (phys << 3)];
                }
#pragma unroll
                for (int mi = 0; mi < 4; ++mi)
#pragma unroll
                    for (int nj = 0; nj < 4; ++nj)
                        acc[mi][nj] = __builtin_amdgcn_mfma_f32_16x16x32_bf16(
                            av[mi], bv[nj], acc[mi][nj], 0, 0, 0);
            }
            __syncthreads();   // Bs free for next k0
        }

        if (MODE == 0) {
            // packed running argmax: (bits(v+2) & ~7) | nj, uint-max; t tracked aside
#pragma unroll
            for (int mi = 0; mi < 4; ++mi)
#pragma unroll
                for (int r = 0; r < 4; ++r) {
                    unsigned m = __float_as_uint(acc[mi][0][r]) & 0xFFFFFFF8u;
#pragma unroll
                    for (int nj = 1; nj < 4; ++nj) {
                        unsigned c = (__float_as_uint(acc[mi][nj][r]) & 0xFFFFFFF8u) | (unsigned)nj;
                        m = c > m ? c : m;
                    }
                    if (m > wbest[mi][r]) { wbest[mi][r] = m; tbest[mi][r] = t; }
                }
        } else {
            const int cb = colbase + (t << 7);
            // diag from raw scores (before exp)
#pragma unroll
            for (int mi = 0; mi < 4; ++mi)
#pragma unroll
                for (int nj = 0; nj < 4; ++nj) {
                    const int gr16 = arow0 + (wr << 6) + (mi << 4);
                    const int gc16 = cb + (wc << 6) + (nj << 4);
                    if (gr16 == gc16) {
#pragma unroll
                        for (int r = 0; r < 4; ++r) {
                            const int rr = ((l >> 4) << 2) + r;
                            if ((l & 15) == rr) dg[gr16 + rr] = acc[mi][nj][r] * 10.0f;
                        }
                    }
                }
#pragma unroll
            for (int mi = 0; mi < 4; ++mi)
#pragma unroll
                for (int nj = 0; nj < 4; ++nj) {
                    v4f tv = acc[mi][nj];
                    tv[0] = exp2f(tv[0] * EXPSCALE);
                    tv[1] = exp2f(tv[1] * EXPSCALE);
                    tv[2] = exp2f(tv[2] * EXPSCALE);
                    tv[3] = exp2f(tv[3] * EXPSCALE);
                    acc[mi][nj] = tv;
                }
#pragma unroll
            for (int mi = 0; mi < 4; ++mi)
#pragma unroll
                for (int r = 0; r < 4; ++r) {
                    float s = 0.f;
#pragma unroll
                    for (int nj = 0; nj < 4; ++nj) s += acc[mi][nj][r];
                    rsum[mi][r] += s;
                }
#pragma unroll
            for (int nj = 0; nj < 4; ++nj) {
                float s = 0.f;
#pragma unroll
                for (int mi = 0; mi < 4; ++mi)
#pragma unroll
                    for (int r = 0; r < 4; ++r) s += acc[mi][nj][r];
                s += __shfl_xor(s, 16); s += __shfl_xor(s, 32);
                if (l < 16) atomicAdd(&sc[cb + (wc << 6) + (nj << 4) + l], s);
            }
        }
    }

    if (MODE == 0) {
#pragma unroll
        for (int mi = 0; mi < 4; ++mi)
#pragma unroll
            for (int r = 0; r < 4; ++r) {
                const unsigned wb = wbest[mi][r];
                const unsigned col = (unsigned)(colbase + (tbest[mi][r] << 7) + (wc << 6) +
                                                (int)((wb & 7u) << 4)) + (l & 15);
                u64_t pk = ((u64_t)wb << 32) | (u64_t)(0xFFFFFFFFu - col);
#pragma unroll
                for (int off = 1; off < 16; off <<= 1) {
                    u64_t o = shfl_xor_u64(pk, off);
                    if (o > pk) pk = o;
                }
                if ((l & 15) == 0)
                    atomicMax(&pk_out[arow0 + (wr << 6) + (mi << 4) + ((l >> 4) << 2) + r], pk);
            }
    } else {
#pragma unroll
        for (int mi = 0; mi < 4; ++mi)
#pragma unroll
            for (int r = 0; r < 4; ++r) {
                float s = rsum[mi][r];
                s += __shfl_xor(s, 1); s += __shfl_xor(s, 2);
                s += __shfl_xor(s, 4); s += __shfl_xor(s, 8);
                if ((l & 15) == 0)
                    atomicAdd(&sr[arow0 + (wr << 6) + (mi << 4) + ((l >> 4) << 2) + r], s);
            }
    }
}

// ---- gather nn rows (grid-stride) ----
__global__ __launch_bounds__(256) void gather_bf(const u64_t* __restrict__ packed,
                                                 const ushort_t* __restrict__ qb,
                                                 ushort_t* __restrict__ nn) {
    const int j = threadIdx.x;
    for (int i = blockIdx.x; i < 2 * BROWS; i += (int)gridDim.x) {
        const unsigned idx = 0xFFFFFFFFu - (unsigned)(packed[i] & 0xFFFFFFFFull);
        nn[(size_t)i * DIMK + j] = qb[(size_t)idx * DIMK + j];
    }
}

__global__ __launch_bounds__(256) void final_loss(const float* __restrict__ d1,
                                                  const float* __restrict__ d2,
                                                  const float* __restrict__ sr1,
                                                  const float* __restrict__ sc1,
                                                  const float* __restrict__ sr2,
                                                  const float* __restrict__ sc2,
                                                  float* __restrict__ out) {
    __shared__ float red[256];
    const int t = threadIdx.x;
    float acc = 0.f;
    for (int i = t; i < BROWS; i += 256) {
        acc += 2.f * (d1[i] + d2[i]) - logf(sr1[i]) - logf(sc1[i]) - logf(sr2[i]) - logf(sc2[i]);
    }
    red[t] = acc;
    __syncthreads();
    for (int s = 128; s > 0; s >>= 1) {
        if (t < s) red[t] += red[t + s];
        __syncthreads();
    }
    if (t == 0) out[0] = -red[0] / (4.0f * (float)BROWS);
}

extern "C" void kernel_launch(void* const* d_in, const int* in_sizes, int n_in,
                              void* d_out, int out_size, void* d_ws, size_t ws_size,
                              hipStream_t stream) {
    const float* f1 = (const float*)d_in[0];
    const float* f2 = (const float*)d_in[1];
    const float* W1 = (const float*)d_in[2];
    const float* b1 = (const float*)d_in[3];
    const float* W2 = (const float*)d_in[4];
    const float* b2 = (const float*)d_in[5];
    const float* queue = (const float*)d_in[6];
    float* out = (float*)d_out;

    char* ws = (char*)d_ws;
    float* h        = (float*)ws;                          // 8 MB (both halves)
    ushort_t* pcat  = (ushort_t*)(ws + (8ull << 20));      // 4 MB: p1 | p2
    ushort_t* nncat = (ushort_t*)(ws + (12ull << 20));     // 4 MB: nn1 | nn2
    ushort_t* qb    = (ushort_t*)(ws + (16ull << 20));     // 16 MB
    u64_t* packed   = (u64_t*)(ws + (32ull << 20));        // 64 KB (8192 rows)
    float* sums     = (float*)(ws + (32ull << 20) + (64ull << 10));   // 64 KB
    float* diag     = (float*)(ws + (32ull << 20) + (128ull << 10));  // 32 KB

    // zero atomic targets (packed argmax + exp sums)
    hipMemsetAsync(packed, 0, (128ull << 10), stream);

    conv_bf16<<<(QN * DIMK) / 2048, 256, 0, stream>>>(queue, qb);

    dim3 gp(BROWS / 16, 2);
    proj_relu16<<<gp, 256, 0, stream>>>(f1, f2, W1, b1, h);
    proj_norm16<<<gp, 256, 0, stream>>>(h, W2, b2, pcat);

    nn_lse<0, 32><<<512, 256, 0, stream>>>(pcat, qb, packed, nullptr, nullptr);

    gather_bf<<<256, 256, 0, stream>>>(packed, qb, nncat);

    nn_lse<1, 4><<<512, 256, 0, stream>>>(nncat, pcat, nullptr, sums, diag);

    final_loss<<<1, 256, 0, stream>>>(diag, diag + BROWS,
                                      sums, sums + BROWS, sums + 2 * BROWS, sums + 3 * BROWS,
                                      out);
}